// Round 4
// baseline (463.116 us; speedup 1.0000x reference)
//
#include <hip/hip_runtime.h>

// SparseInputLayer: inputs [B, ND*(1+NS)] fp32.
//  - cols [0,64): channel indices (float-encoded ints in [0,384))
//  - cols [64, ...): data rows x[b][j][s]
// out[b][c][s] = sum_{j: idx[b][j]==c} x[b][j][s], shape [2048,384,121,1] fp32.
//
// Two KERNELS (stream-ordered), not two phases in one block:
//  k1: pure grid-stride float4 zero-fill — same structure as rocclr
//      fillBufferAligned, which sustains 6.2 TB/s on this exact buffer.
//      No LDS, no barriers, no prologue ahead of the first store.
//  k2: sparse overwrite — one block per batch builds per-channel 64-bit
//      membership masks in LDS, compacts the ~59 nonempty channels, then
//      one wave per channel rewrites its 484 B row (wave-uniform bit-walk).

#define BATCH 2048
#define N_DENSE 64
#define N_SAMPLES 121
#define N_CHANNELS 384
#define ROW_IN (N_DENSE * (1 + N_SAMPLES)) // 7808 floats per input row
#define ROW_OUT (N_CHANNELS * N_SAMPLES)   // 46464 floats per output row
#define BLOCK 256
#define FILL_BLOCKS 4096
#define NVEC_TOTAL ((BATCH * ROW_OUT) / 4) // 23,789,568 float4

typedef float vfloat4 __attribute__((ext_vector_type(4)));

__global__ __launch_bounds__(BLOCK) void zero_fill_kernel(float* __restrict__ out) {
  const vfloat4 z = {0.f, 0.f, 0.f, 0.f};
  vfloat4* __restrict__ ov = reinterpret_cast<vfloat4*>(out);
  const int step = FILL_BLOCKS * BLOCK;
  for (int q = blockIdx.x * BLOCK + threadIdx.x; q < NVEC_TOTAL; q += step)
    ov[q] = z; // aligned 16B/lane, fully coalesced, dependence-free
}

__global__ __launch_bounds__(BLOCK) void scatter_kernel(
    const float* __restrict__ in, float* __restrict__ out) {
  __shared__ unsigned long long mask[N_CHANNELS];
  __shared__ unsigned short list[N_CHANNELS]; // compacted nonempty channels
  __shared__ int nlist;

  const int b = blockIdx.x;
  const int tid = threadIdx.x;

  for (int c = tid; c < N_CHANNELS; c += BLOCK) mask[c] = 0ull;
  if (tid == 0) nlist = 0;
  __syncthreads();

  if (tid < N_DENSE) {
    const int c = (int)in[(size_t)b * ROW_IN + tid];
    atomicOr(&mask[c], 1ull << tid);
  }
  __syncthreads();

  for (int c = tid; c < N_CHANNELS; c += BLOCK) {
    if (mask[c] != 0ull) {
      const int p = atomicAdd(&nlist, 1);
      list[p] = (unsigned short)c;
    }
  }
  __syncthreads();

  const float* __restrict__ x = in + (size_t)b * ROW_IN + N_DENSE; // [64][121]
  float* __restrict__ o = out + (size_t)b * ROW_OUT;               // [384][121]

  const int wave = tid >> 6;
  const int lane = tid & 63;
  const int s = lane * 2;
  const bool has0 = (s < N_SAMPLES);      // lanes 61..63 idle
  const bool has1 = (s + 1 < N_SAMPLES);  // lane 60 handles 1 elt
  const int s0 = has0 ? s : 0;            // clamp: keep gather loads in-bounds
  const int s1 = has1 ? s + 1 : 0;
  const int n = nlist;

  for (int i = wave; i < n; i += BLOCK / 64) {
    const int c = __builtin_amdgcn_readfirstlane((int)list[i]);
    unsigned long long m = mask[c]; // wave-uniform
    float a0 = 0.f, a1 = 0.f;
    while (m) { // uniform trip count, avg ~1.1 per nonempty channel
      const int j = __builtin_ctzll(m);
      m &= m - 1;
      a0 += x[j * N_SAMPLES + s0]; // coalesced 484 B row read
      a1 += x[j * N_SAMPLES + s1];
    }
    float* oc = o + c * N_SAMPLES;
    if (has1) {
      oc[s] = a0;
      oc[s + 1] = a1;
    } else if (has0) {
      oc[s] = a0;
    }
  }
}

extern "C" void kernel_launch(void* const* d_in, const int* in_sizes, int n_in,
                              void* d_out, int out_size, void* d_ws, size_t ws_size,
                              hipStream_t stream) {
  const float* in = (const float*)d_in[0];
  float* out = (float*)d_out;
  zero_fill_kernel<<<FILL_BLOCKS, BLOCK, 0, stream>>>(out);
  scatter_kernel<<<BATCH, BLOCK, 0, stream>>>(in, out);
}